// Round 1
// baseline (471.984 us; speedup 1.0000x reference)
//
#include <hip/hip_runtime.h>

#define EPS 1e-8f
#define TAU_INV 10.0f
#define NITER 10

// One wave (64 lanes) per 32x32 matrix. K held in registers as 4 float4 per
// lane: K[j] = row (8j + (lane>>3)), cols 4*(lane&7)..+3. Sinkhorn iterations
// run on scaling vectors a (rows), b (cols); M = diag(a) K diag(b) written once.
__global__ __launch_bounds__(256) void
SinkhornProjection_60962765799638_kernel(const float* __restrict__ H,
                                         float* __restrict__ out, int n_mat) {
    const int lane = threadIdx.x & 63;
    const int wv = threadIdx.x >> 6;
    const long long mat = (long long)blockIdx.x * 4 + wv;
    if (mat >= n_mat) return;

    const float* __restrict__ src = H + mat * 1024;
    float* __restrict__ dst = out + mat * 1024;

    float4 K[4];
#pragma unroll
    for (int j = 0; j < 4; ++j)
        K[j] = *reinterpret_cast<const float4*>(src + j * 256 + lane * 4);

    // K = max(exp(H/tau), EPS)
#pragma unroll
    for (int j = 0; j < 4; ++j) {
        K[j].x = fmaxf(__expf(K[j].x * TAU_INV), EPS);
        K[j].y = fmaxf(__expf(K[j].y * TAU_INV), EPS);
        K[j].z = fmaxf(__expf(K[j].z * TAU_INV), EPS);
        K[j].w = fmaxf(__expf(K[j].w * TAU_INV), EPS);
    }

    float a[4] = {1.f, 1.f, 1.f, 1.f};          // a[j] for row 8j + (lane>>3)
    float4 b = make_float4(1.f, 1.f, 1.f, 1.f); // b for cols 4*(lane&7)..+3

#pragma unroll
    for (int it = 0; it < NITER; ++it) {
        // ---- row normalize: a <- a / (a*(K b) + EPS) ----
        float s[4];
#pragma unroll
        for (int t = 0; t < 4; ++t) {
            float v = fmaf(K[t].x, b.x,
                      fmaf(K[t].y, b.y,
                      fmaf(K[t].z, b.z, K[t].w * b.w)));
            v += __shfl_xor(v, 1);
            v += __shfl_xor(v, 2);
            v += __shfl_xor(v, 4);
            s[t] = v;
        }
#pragma unroll
        for (int t = 0; t < 4; ++t)
            a[t] = a[t] * __builtin_amdgcn_rcpf(fmaf(a[t], s[t], EPS));

        // ---- col normalize: b <- b / (b*(K^T a) + EPS) ----
        float4 p;
        p.x = fmaf(a[0], K[0].x, fmaf(a[1], K[1].x, fmaf(a[2], K[2].x, a[3] * K[3].x)));
        p.y = fmaf(a[0], K[0].y, fmaf(a[1], K[1].y, fmaf(a[2], K[2].y, a[3] * K[3].y)));
        p.z = fmaf(a[0], K[0].z, fmaf(a[1], K[1].z, fmaf(a[2], K[2].z, a[3] * K[3].z)));
        p.w = fmaf(a[0], K[0].w, fmaf(a[1], K[1].w, fmaf(a[2], K[2].w, a[3] * K[3].w)));
#pragma unroll
        for (int m = 8; m <= 32; m <<= 1) {
            p.x += __shfl_xor(p.x, m);
            p.y += __shfl_xor(p.y, m);
            p.z += __shfl_xor(p.z, m);
            p.w += __shfl_xor(p.w, m);
        }
        b.x = b.x * __builtin_amdgcn_rcpf(fmaf(b.x, p.x, EPS));
        b.y = b.y * __builtin_amdgcn_rcpf(fmaf(b.y, p.y, EPS));
        b.z = b.z * __builtin_amdgcn_rcpf(fmaf(b.z, p.z, EPS));
        b.w = b.w * __builtin_amdgcn_rcpf(fmaf(b.w, p.w, EPS));
    }

    // ---- write M = a * K * b, same coalesced layout as the load ----
#pragma unroll
    for (int j = 0; j < 4; ++j) {
        float4 m;
        m.x = a[j] * K[j].x * b.x;
        m.y = a[j] * K[j].y * b.y;
        m.z = a[j] * K[j].z * b.z;
        m.w = a[j] * K[j].w * b.w;
        *reinterpret_cast<float4*>(dst + j * 256 + lane * 4) = m;
    }
}

extern "C" void kernel_launch(void* const* d_in, const int* in_sizes, int n_in,
                              void* d_out, int out_size, void* d_ws, size_t ws_size,
                              hipStream_t stream) {
    const float* H = (const float*)d_in[0];
    float* out = (float*)d_out;
    const int n_mat = in_sizes[0] / 1024;
    const int blocks = (n_mat + 3) / 4;
    hipLaunchKernelGGL(SinkhornProjection_60962765799638_kernel,
                       dim3(blocks), dim3(256), 0, stream, H, out, n_mat);
}